// Round 9
// baseline (400.471 us; speedup 1.0000x reference)
//
#include <hip/hip_runtime.h>
#include <math.h>

#define Bz 16
#define Sz 512
#define Dz 768
#define Hz 12
#define HDz 64
#define Kz 16
#define NSz 128
#define Rz 32

typedef __attribute__((ext_vector_type(4))) float f32x4;
typedef __attribute__((ext_vector_type(8))) short bf16x8;

__device__ __forceinline__ unsigned short f2bf(float f) {
    unsigned u = __float_as_uint(f);
    return (unsigned short)((u + 0x7fffu + ((u >> 16) & 1u)) >> 16);
}
__device__ __forceinline__ float bf2f(unsigned short s) {
    return __uint_as_float(((unsigned)s) << 16);
}
__device__ __forceinline__ unsigned pk2(float a, float b) {
    return (unsigned)f2bf(a) | ((unsigned)f2bf(b) << 16);
}
__device__ __forceinline__ void gload_lds16(const void* g, void* l) {
    __builtin_amdgcn_global_load_lds(
        (const __attribute__((address_space(1))) unsigned int*)g,
        (__attribute__((address_space(3))) unsigned int*)l, 16, 0, 0);
}

// ---------------- fused x->bf16 + row squared norms (one wave per row) ----------------
__global__ __launch_bounds__(256) void xrn_k(const float* __restrict__ x, short* __restrict__ xb,
                                             float* __restrict__ xsq) {
    int wv = threadIdx.x >> 6, lane = threadIdx.x & 63;
    int row = blockIdx.x * 4 + wv;
    const float* r = x + (size_t)row * Dz;
    unsigned long long* dst = (unsigned long long*)(xb + (size_t)row * Dz);
    float s = 0.f;
#pragma unroll
    for (int j = 0; j < 3; j++) {
        float4 v = ((const float4*)r)[lane + j * 64];
        s += v.x * v.x + v.y * v.y + v.z * v.z + v.w * v.w;
        dst[lane + j * 64] = (unsigned long long)pk2(v.x, v.y) | ((unsigned long long)pk2(v.z, v.w) << 32);
    }
#pragma unroll
    for (int off = 32; off > 0; off >>= 1) s += __shfl_xor(s, off, 64);
    if (lane == 0) xsq[row] = s;
}

// ---------------- prep: 4 weight transposes (fp32->bf16, [n][k]) + sample gather ----------------
__device__ __forceinline__ void wtrans_body(const float* __restrict__ src, short* __restrict__ dst,
                                            int K, int N, int k0, int n0, int tid,
                                            float (*t)[65]) {
#pragma unroll
    for (int i = 0; i < 16; i++) {
        int e = tid + 256 * i;
        int kk = e >> 6, nn = e & 63;
        t[kk][nn] = src[(size_t)(k0 + kk) * N + n0 + nn];
    }
    __syncthreads();
#pragma unroll
    for (int i = 0; i < 16; i++) {
        int e = tid + 256 * i;
        int nn = e >> 6, kk = e & 63;
        dst[(size_t)(n0 + nn) * K + k0 + kk] = (short)f2bf(t[kk][nn]);
    }
}

__global__ __launch_bounds__(256) void prep_k(const float* __restrict__ ipw, const float* __restrict__ opw,
                                              const float* __restrict__ f1w, const float* __restrict__ f2w,
                                              short* __restrict__ wT_ip, short* __restrict__ wT_op,
                                              short* __restrict__ wT_f1, short* __restrict__ wT_f2,
                                              const float* __restrict__ x, const int* __restrict__ sidx,
                                              short* __restrict__ scb) {
    __shared__ float t[64][65];
    int bid = blockIdx.x, tid = threadIdx.x;
    if (bid < 432) {
        int lo = bid, tx = lo % 36, ty = lo / 36;
        wtrans_body(ipw, wT_ip, Dz, 3 * Dz, ty * 64, tx * 64, tid, t);
    } else if (bid < 576) {
        int lo = bid - 432, tx = lo % 12, ty = lo / 12;
        wtrans_body(opw, wT_op, Dz, Dz, ty * 64, tx * 64, tid, t);
    } else if (bid < 864) {
        int lo = bid - 576, tx = lo % 24, ty = lo / 24;
        wtrans_body(f1w, wT_f1, Dz, 2 * Dz, ty * 64, tx * 64, tid, t);
    } else if (bid < 1152) {
        int lo = bid - 864, tx = lo % 12, ty = lo / 12;
        wtrans_body(f2w, wT_f2, 2 * Dz, Dz, ty * 64, tx * 64, tid, t);
    } else {
        int gb = bid - 1152;
        int row = gb * 16 + (tid >> 4);
        int b = row >> 7, jj = row & 127;
        const float* src = x + ((size_t)(b * Sz) + sidx[jj]) * Dz;
        unsigned long long* dr = (unsigned long long*)(scb + (size_t)row * Dz);
        int l16 = tid & 15;
#pragma unroll
        for (int j = 0; j < 12; j++) {
            int idx = j * 16 + l16;
            float4 v = ((const float4*)src)[idx];
            dr[idx] = (unsigned long long)pk2(v.x, v.y) | ((unsigned long long)pk2(v.z, v.w) << 32);
        }
    }
}

// ---------------- rank-select K smallest -> per-row {sum, sumsq, min, max16} ----------------
__global__ __launch_bounds__(128) void knnstat_k(const float* __restrict__ D, float4* __restrict__ rowred) {
    __shared__ float dv[NSz];
    __shared__ float red[NSz], red2[NSz];
    __shared__ float rmin, rmax;
    int tid = threadIdx.x, row = blockIdx.x;
    float dist = D[(size_t)row * NSz + tid];
    dv[tid] = dist;
    __syncthreads();
    int rank = 0;
#pragma unroll 8
    for (int j = 0; j < NSz; j++) {
        float o = dv[j];
        rank += (o < dist) || (o == dist && j < tid);
    }
    if (rank == 0) rmin = dist;
    if (rank == Kz - 1) rmax = dist;
    red[tid] = (rank < Kz) ? dist : 0.f;
    red2[tid] = (rank < Kz) ? dist * dist : 0.f;
    __syncthreads();
    for (int st = 64; st > 0; st >>= 1) {
        if (tid < st) { red[tid] += red[tid + st]; red2[tid] += red2[tid + st]; }
        __syncthreads();
    }
    if (tid == 0) rowred[row] = make_float4(red[0], red2[0], rmin, rmax);
}

// ---------------- per-batch reduce + stats -> landscape MLP -> topo vector ----------------
__global__ __launch_bounds__(256) void land_topo_k(const float4* __restrict__ rowred,
                                                   const float* __restrict__ w1, const float* __restrict__ b1,
                                                   const float* __restrict__ w2, const float* __restrict__ b2,
                                                   const float* __restrict__ wd0, const float* __restrict__ bd0,
                                                   const float* __restrict__ topo_w, const float* __restrict__ topo_b,
                                                   const float* gate, float* __restrict__ topo_add) {
    __shared__ float4 red4[256];
    __shared__ float st[6];
    __shared__ float h[Dz / 4];
    __shared__ float l2[Rz];
    __shared__ float land[Rz];
    int b = blockIdx.x, tid = threadIdx.x;
    float4 a = rowred[b * Sz + tid];
    float4 c = rowred[b * Sz + 256 + tid];
    float4 r;
    r.x = a.x + c.x; r.y = a.y + c.y;
    r.z = fminf(a.z, c.z); r.w = fmaxf(a.w, c.w);
    red4[tid] = r;
    __syncthreads();
    for (int stp = 128; stp > 0; stp >>= 1) {
        if (tid < stp) {
            float4 p = red4[tid], q = red4[tid + stp];
            p.x += q.x; p.y += q.y; p.z = fminf(p.z, q.z); p.w = fmaxf(p.w, q.w);
            red4[tid] = p;
        }
        __syncthreads();
    }
    if (tid == 0) {
        const double N = (double)(Sz * Kz);
        double sum = (double)red4[0].x, sumsq = (double)red4[0].y;
        double mean = sum / N;
        double var = (sumsq - N * mean * mean) / (N - 1.0);
        float sd = (float)sqrt(fmax(var, 0.0));
        float m = (float)mean;
        st[0] = m; st[1] = sd;
        st[2] = red4[0].z; st[3] = red4[0].w;
        st[4] = m * 0.5f; st[5] = sd * 0.5f;
    }
    __syncthreads();
    if (tid < Dz / 4) {
        float a1 = b1[tid];
#pragma unroll
        for (int i = 0; i < 6; i++) a1 += st[i] * w1[i * (Dz / 4) + tid];
        h[tid] = fmaxf(a1, 0.f);
    }
    __syncthreads();
    if (tid < Rz) {
        float a1 = b2[tid];
        for (int i = 0; i < Dz / 4; i++) a1 += h[i] * w2[i * Rz + tid];
        l2[tid] = a1;
    }
    __syncthreads();
    if (tid < Rz) {
        float a1 = bd0[tid];
#pragma unroll
        for (int i = 0; i < Rz; i++) a1 += l2[i] * wd0[i * Rz + tid];
        land[tid] = a1;
    }
    __syncthreads();
    float g = gate[0];
    for (int d = tid; d < Dz; d += 256) {
        float a1 = topo_b[d];
#pragma unroll
        for (int i = 0; i < Rz; i++) a1 += land[i] * topo_w[i * Dz + d];
        topo_add[b * Dz + d] = g * a1;
    }
}

// ---------------- MFMA GEMM 256x128 tile, 8 waves: C = A[M,K] @ (BT[N,K])^T + bias ----------------
// EPI: 1 = GELU->bf16 (restaged), 2 = qkv scatter (restaged), 3 = bf16 store (restaged),
//      4 = LSH distance epilogue (fp32 sqrt, batched BT)
// 1D grid with XCD-bijective swizzle; gx = #n-tiles.
// LDS per buffer: A 256x32 bf16 (16KB) at 0, B 128x32 bf16 (8KB) at short-off 8192. 2 buffers = 48KB.
__device__ __forceinline__ void stage_tile256(const short* __restrict__ A, const short* __restrict__ B,
                                              int ldk, int m0, int n0, int k0,
                                              short* lbase, int w, int l) {
#pragma unroll
    for (int si = 0; si < 3; si++) {
        int s = si * 8 + w;
        if (s < 16) {
            int r = s * 16 + (l >> 2);
            int qg = (l & 3) ^ ((r >> 1) & 3);
            gload_lds16(A + (size_t)(m0 + r) * ldk + k0 + qg * 8, lbase + s * 512);
        } else {
            int r = (s - 16) * 16 + (l >> 2);
            int qg = (l & 3) ^ ((r >> 1) & 3);
            gload_lds16(B + (size_t)(n0 + r) * ldk + k0 + qg * 8, lbase + 8192 + (s - 16) * 512);
        }
    }
}

template <int EPI>
__global__ __launch_bounds__(512) void mgemm_k(const short* __restrict__ A, const short* __restrict__ BT,
                                               const float* __restrict__ bias,
                                               float* __restrict__ C, short* __restrict__ Cb,
                                               int N, int Kd, int gx,
                                               short* __restrict__ qo, short* __restrict__ ko,
                                               short* __restrict__ vT,
                                               const int* __restrict__ sidx, const float* __restrict__ xsq) {
    __shared__ short lds[2][12288];
    int tid = threadIdx.x, w = tid >> 6, l = tid & 63;
    int nwg = gridDim.x, q = nwg >> 3;
    int orig = (blockIdx.x & 7) * q + (blockIdx.x >> 3);
    int m0 = (orig / gx) * 256, n0 = (orig % gx) * 128;
    const short* BTb = BT;
    if (EPI == 4) BTb += (size_t)(m0 >> 9) * NSz * Kd;
    int wr = w >> 1, wc = w & 1, g = l >> 4, ql = l & 15;
    f32x4 acc[4][4];
#pragma unroll
    for (int i = 0; i < 4; i++)
#pragma unroll
        for (int j = 0; j < 4; j++) acc[i][j] = (f32x4){0.f, 0.f, 0.f, 0.f};
    stage_tile256(A, BTb, Kd, m0, n0, 0, lds[0], w, l);
    __syncthreads();
    int nst = Kd / 32;
    for (int t = 0; t < nst; t++) {
        int buf = t & 1;
        if (t + 1 < nst)
            stage_tile256(A, BTb, Kd, m0, n0, (t + 1) * 32, lds[buf ^ 1], w, l);
        bf16x8 af[4], bfr[4];
#pragma unroll
        for (int i = 0; i < 4; i++) {
            int r = wr * 64 + i * 16 + ql;
            af[i] = *(const bf16x8*)((const char*)lds[buf] + r * 64 + ((g ^ ((r >> 1) & 3)) << 4));
        }
#pragma unroll
        for (int j = 0; j < 4; j++) {
            int r = wc * 64 + j * 16 + ql;
            bfr[j] = *(const bf16x8*)((const char*)lds[buf] + 16384 + r * 64 + ((g ^ ((r >> 1) & 3)) << 4));
        }
#pragma unroll
        for (int i = 0; i < 4; i++)
#pragma unroll
            for (int j = 0; j < 4; j++)
                acc[i][j] = __builtin_amdgcn_mfma_f32_16x16x32_bf16(af[i], bfr[j], acc[i][j], 0, 0, 0);
        __syncthreads();
    }

    if (EPI == 4) {
#pragma unroll
        for (int i = 0; i < 4; i++) {
            int rowb = m0 + wr * 64 + i * 16 + g * 4;
            int bb = rowb >> 9;
#pragma unroll
            for (int j = 0; j < 4; j++) {
                int col = wc * 64 + j * 16 + ql;
                float ssq = xsq[(bb << 9) + sidx[col]];
#pragma unroll
                for (int r = 0; r < 4; r++) {
                    int row = rowb + r;
                    float d2 = xsq[row] + ssq - 2.f * acc[i][j][r];
                    C[(size_t)row * NSz + col] = sqrtf(fmaxf(d2, 0.f));
                }
            }
        }
    } else {
        // restage C-tile in two 128-row halves (128x128 bf16 = 32 KB) through staging LDS
        short* cl = lds[0];
        const int part = (EPI == 2) ? (n0 / Dz) : 0;
        const bool cm = (EPI == 2) && (part == 2);   // uniform per block
#pragma unroll
        for (int h = 0; h < 2; h++) {
            if ((w >> 2) == h) {
                int wrl = wr & 1;    // 64-row band within this half
                if (!cm) {
#pragma unroll
                    for (int i = 0; i < 4; i++) {
#pragma unroll
                        for (int j = 0; j < 4; j++) {
                            int colL = wc * 64 + j * 16 + ql;
                            float bsv = bias[n0 + colL];
#pragma unroll
                            for (int r = 0; r < 4; r++) {
                                int rowL = wrl * 64 + i * 16 + g * 4 + r;
                                float val = acc[i][j][r] + bsv;
                                if (EPI == 1) val = 0.5f * val * (1.f + erff(val * 0.70710678118654752f));
                                cl[rowL * 128 + (((colL >> 3) ^ (rowL & 15)) << 3) + (colL & 7)] = (short)f2bf(val);
                            }
                        }
                    }
                } else {
#pragma unroll
                    for (int i = 0; i < 4; i++) {
#pragma unroll
                        for (int j = 0; j < 4; j++) {
                            int colL = wc * 64 + j * 16 + ql;
                            float bsv = bias[n0 + colL];
                            int row4 = wrl * 64 + i * 16 + g * 4;
                            unsigned long long u =
                                (unsigned long long)pk2(acc[i][j][0] + bsv, acc[i][j][1] + bsv)
                              | ((unsigned long long)pk2(acc[i][j][2] + bsv, acc[i][j][3] + bsv) << 32);
                            *(unsigned long long*)((char*)cl +
                                colL * 256 + (((row4 >> 3) ^ (colL & 15)) << 4) + (row4 & 7) * 2) = u;
                        }
                    }
                }
            }
            __syncthreads();
            int rbase = m0 + h * 128;
#pragma unroll
            for (int it = 0; it < 4; it++) {
                int c = tid + 512 * it;
                int a = c >> 4, sl = c & 15;
                bf16x8 vv = *(const bf16x8*)(cl + a * 128 + ((sl ^ (a & 15)) << 3));
                if (EPI == 1 || EPI == 3) {
                    *(bf16x8*)(Cb + (size_t)(rbase + a) * N + n0 + sl * 8) = vv;
                } else if (!cm) {
                    int rr = rbase + a;
                    int b = rr >> 9, s = rr & 511;
                    int hh = ((n0 % Dz) >> 6) + (sl >> 3);
                    short* dst = part ? ko : qo;
                    *(bf16x8*)(dst + (((size_t)(b * Hz + hh)) * Sz + s) * HDz + (sl & 7) * 8) = vv;
                } else {
                    int wi = (n0 - 2 * Dz) + a;
                    int hh = wi >> 6, hd = wi & 63;
                    int b = rbase >> 9, s0 = (rbase & 511) + sl * 8;
                    *(bf16x8*)(vT + ((size_t)(b * Hz + hh) * HDz + hd) * Sz + s0) = vv;
                }
            }
            if (h == 0) __syncthreads();
        }
    }
}

// ---------------- MFMA attention v4: LDS-staged K/V chunks, XCD-local heads ----------------
__global__ __launch_bounds__(256, 4) void attn4_k(const short* __restrict__ Q, const short* __restrict__ Kt,
                                                  const short* __restrict__ Vt, short* __restrict__ O) {
    __shared__ short kl[2][4096];
    __shared__ short vl[2][4096];
    __shared__ char plds[4][2048];
    int tid = threadIdx.x, w = tid >> 6, l = tid & 63;
    int bh = blockIdx.x % (Bz * Hz), qt = blockIdx.x / (Bz * Hz);
    int g = l >> 4, ql = l & 15;
    const short* qb = Q + (size_t)bh * (Sz * HDz) + (size_t)(qt * 64 + w * 16) * HDz;
    const short* kb = Kt + (size_t)bh * (Sz * HDz);
    const short* vb = Vt + (size_t)bh * (HDz * Sz);
    bf16x8 qf0 = *(const bf16x8*)(qb + (size_t)ql * HDz + g * 8);
    bf16x8 qf1 = *(const bf16x8*)(qb + (size_t)ql * HDz + 32 + g * 8);
    f32x4 oa[4];
#pragma unroll
    for (int m = 0; m < 4; m++) oa[m] = (f32x4){0.f, 0.f, 0.f, 0.f};
    float psum = 0.f;

    auto stage = [&](int c, int bb) {
#pragma unroll
        for (int it = 0; it < 2; it++) {
            int i = (it * 4 + w) * 64 + l;
            int row = i >> 3;
            int ss = (i & 7) ^ (row & 7);
            gload_lds16(kb + (size_t)(c * 64 + row) * HDz + ss * 8,
                        (char*)kl[bb] + (it * 4 + w) * 1024);
            gload_lds16(vb + (size_t)row * Sz + c * 64 + ss * 8,
                        (char*)vl[bb] + (it * 4 + w) * 1024);
        }
    };

    stage(0, 0);
    __syncthreads();
    char* pw = plds[w];
#pragma unroll
    for (int c = 0; c < 8; c++) {
        int cur = c & 1;
        if (c < 7) stage(c + 1, cur ^ 1);
        const char* kc = (const char*)kl[cur];
        const char* vc = (const char*)vl[cur];
#pragma unroll
        for (int tl = 0; tl < 4; tl++) {
            int row = tl * 16 + ql;
            bf16x8 a0 = *(const bf16x8*)(kc + row * 128 + ((g ^ (ql & 7)) << 4));
            bf16x8 a1 = *(const bf16x8*)(kc + row * 128 + (((4 + g) ^ (ql & 7)) << 4));
            f32x4 s4 = (f32x4){0.f, 0.f, 0.f, 0.f};
            s4 = __builtin_amdgcn_mfma_f32_16x16x32_bf16(a0, qf0, s4, 0, 0, 0);
            s4 = __builtin_amdgcn_mfma_f32_16x16x32_bf16(a1, qf1, s4, 0, 0, 0);
            float e0 = __expf(s4[0] * 0.125f);
            float e1 = __expf(s4[1] * 0.125f);
            float e2 = __expf(s4[2] * 0.125f);
            float e3 = __expf(s4[3] * 0.125f);
            psum += (e0 + e1) + (e2 + e3);
            int slot = (tl * 2 + (g >> 1)) ^ (ql & 7);
            *(unsigned long long*)(pw + ql * 128 + slot * 16 + (g & 1) * 8)
                = (unsigned long long)pk2(e0, e1) | ((unsigned long long)pk2(e2, e3) << 32);
        }
#pragma unroll
        for (int s = 0; s < 2; s++) {
            int slot = (s * 4 + g) ^ (ql & 7);
            bf16x8 pb = *(const bf16x8*)(pw + ql * 128 + slot * 16);
#pragma unroll
            for (int m = 0; m < 4; m++) {
                int row = m * 16 + ql;
                bf16x8 va = *(const bf16x8*)(vc + row * 128 + (((s * 4 + g) ^ (ql & 7)) << 4));
                oa[m] = __builtin_amdgcn_mfma_f32_16x16x32_bf16(va, pb, oa[m], 0, 0, 0);
            }
        }
        __syncthreads();
    }
    psum += __shfl_xor(psum, 16, 64);
    psum += __shfl_xor(psum, 32, 64);
    float inv = 1.f / psum;
    int b = bh / Hz, h = bh % Hz;
    int s = qt * 64 + w * 16 + ql;
#pragma unroll
    for (int m = 0; m < 4; m++)
#pragma unroll
        for (int j = 0; j < 2; j++) {
            float v0 = oa[m][j * 2] * inv, v1 = oa[m][j * 2 + 1] * inv;
            unsigned u = pk2(v0, v1);
            int d = h * 64 + m * 16 + g * 4 + j * 2;
            *(unsigned*)((char*)O + 2 * ((size_t)(b * Sz + s) * Dz + d)) = u;
        }
}

// ---------------- LN1 (wave/row, vectorized, one-pass): x1b = bf16(LN(x + bf2f(ap) + topo)) ----------------
__global__ __launch_bounds__(256) void ln1_k(const float* __restrict__ x, const short* __restrict__ ap,
                                             const float* __restrict__ topo,
                                             const float* __restrict__ gam, const float* __restrict__ bet,
                                             short* __restrict__ x1b) {
    int wv = threadIdx.x >> 6, lane = threadIdx.x & 63;
    int row = blockIdx.x * 4 + wv, b = row >> 9;
    const float4* xr = (const float4*)(x + (size_t)row * Dz);
    const float4* tr = (const float4*)(topo + (size_t)b * Dz);
    const unsigned long long* ar = (const unsigned long long*)(ap + (size_t)row * Dz);
    float v[12];
    float sum = 0.f, ssq = 0.f;
#pragma unroll
    for (int j = 0; j < 3; j++) {
        int idx = lane + j * 64;
        float4 xv = xr[idx];
        float4 tv = tr[idx];
        unsigned long long av = ar[idx];
        float v0 = xv.x + bf2f((unsigned short)av) + tv.x;
        float v1 = xv.y + bf2f((unsigned short)(av >> 16)) + tv.y;
        float v2 = xv.z + bf2f((unsigned short)(av >> 32)) + tv.z;
        float v3 = xv.w + bf2f((unsigned short)(av >> 48)) + tv.w;
        v[j * 4 + 0] = v0; v[j * 4 + 1] = v1; v[j * 4 + 2] = v2; v[j * 4 + 3] = v3;
        sum += (v0 + v1) + (v2 + v3);
        ssq += (v0 * v0 + v1 * v1) + (v2 * v2 + v3 * v3);
    }
#pragma unroll
    for (int off = 32; off > 0; off >>= 1) {
        sum += __shfl_xor(sum, off, 64);
        ssq += __shfl_xor(ssq, off, 64);
    }
    float mean = sum * (1.f / (float)Dz);
    float var = ssq * (1.f / (float)Dz) - mean * mean;
    float inv = 1.f / sqrtf(var + 1e-5f);
    unsigned long long* dst = (unsigned long long*)(x1b + (size_t)row * Dz);
#pragma unroll
    for (int j = 0; j < 3; j++) {
        int idx = lane + j * 64;
        float4 gv = ((const float4*)gam)[idx];
        float4 bv = ((const float4*)bet)[idx];
        float o0 = (v[j * 4 + 0] - mean) * inv * gv.x + bv.x;
        float o1 = (v[j * 4 + 1] - mean) * inv * gv.y + bv.y;
        float o2 = (v[j * 4 + 2] - mean) * inv * gv.z + bv.z;
        float o3 = (v[j * 4 + 3] - mean) * inv * gv.w + bv.w;
        dst[idx] = (unsigned long long)pk2(o0, o1) | ((unsigned long long)pk2(o2, o3) << 32);
    }
}

// ---------------- LN2 (wave/row, vectorized, one-pass): out = LN(bf2f(x1b) + bf2f(f2)) ----------------
__global__ __launch_bounds__(256) void ln2_k(const short* __restrict__ x1b, const short* __restrict__ f2,
                                             const float* __restrict__ gam, const float* __restrict__ bet,
                                             float* __restrict__ out) {
    int wv = threadIdx.x >> 6, lane = threadIdx.x & 63;
    int row = blockIdx.x * 4 + wv;
    const unsigned long long* xr = (const unsigned long long*)(x1b + (size_t)row * Dz);
    const unsigned long long* fr = (const unsigned long long*)(f2 + (size_t)row * Dz);
    float v[12];
    float sum = 0.f, ssq = 0.f;
#pragma unroll
    for (int j = 0; j < 3; j++) {
        int idx = lane + j * 64;
        unsigned long long xv = xr[idx];
        unsigned long long fv = fr[idx];
        float v0 = bf2f((unsigned short)xv) + bf2f((unsigned short)fv);
        float v1 = bf2f((unsigned short)(xv >> 16)) + bf2f((unsigned short)(fv >> 16));
        float v2 = bf2f((unsigned short)(xv >> 32)) + bf2f((unsigned short)(fv >> 32));
        float v3 = bf2f((unsigned short)(xv >> 48)) + bf2f((unsigned short)(fv >> 48));
        v[j * 4 + 0] = v0; v[j * 4 + 1] = v1; v[j * 4 + 2] = v2; v[j * 4 + 3] = v3;
        sum += (v0 + v1) + (v2 + v3);
        ssq += (v0 * v0 + v1 * v1) + (v2 * v2 + v3 * v3);
    }
#pragma unroll
    for (int off = 32; off > 0; off >>= 1) {
        sum += __shfl_xor(sum, off, 64);
        ssq += __shfl_xor(ssq, off, 64);
    }
    float mean = sum * (1.f / (float)Dz);
    float var = ssq * (1.f / (float)Dz) - mean * mean;
    float inv = 1.f / sqrtf(var + 1e-5f);
    float4* dst = (float4*)(out + (size_t)row * Dz);
#pragma unroll
    for (int j = 0; j < 3; j++) {
        int idx = lane + j * 64;
        float4 gv = ((const float4*)gam)[idx];
        float4 bv = ((const float4*)bet)[idx];
        float4 o;
        o.x = (v[j * 4 + 0] - mean) * inv * gv.x + bv.x;
        o.y = (v[j * 4 + 1] - mean) * inv * gv.y + bv.y;
        o.z = (v[j * 4 + 2] - mean) * inv * gv.z + bv.z;
        o.w = (v[j * 4 + 3] - mean) * inv * gv.w + bv.w;
        dst[idx] = o;
    }
}

extern "C" void kernel_launch(void* const* d_in, const int* in_sizes, int n_in,
                              void* d_out, int out_size, void* d_ws, size_t ws_size,
                              hipStream_t stream) {
    const float* x          = (const float*)d_in[0];
    const int*   sidx       = (const int*)d_in[1];
    const float* w1         = (const float*)d_in[2];
    const float* b1         = (const float*)d_in[3];
    const float* w2         = (const float*)d_in[4];
    const float* b2         = (const float*)d_in[5];
    const float* wd0        = (const float*)d_in[6];
    const float* bd0        = (const float*)d_in[7];
    const float* in_proj_w  = (const float*)d_in[10];
    const float* in_proj_b  = (const float*)d_in[11];
    const float* out_proj_w = (const float*)d_in[12];
    const float* out_proj_b = (const float*)d_in[13];
    const float* topo_w     = (const float*)d_in[14];
    const float* topo_b     = (const float*)d_in[15];
    const float* gate       = (const float*)d_in[16];
    const float* ln1_g      = (const float*)d_in[17];
    const float* ln1_b      = (const float*)d_in[18];
    const float* ln2_g      = (const float*)d_in[19];
    const float* ln2_b      = (const float*)d_in[20];
    const float* ffn_w1     = (const float*)d_in[21];
    const float* ffn_b1     = (const float*)d_in[22];
    const float* ffn_w2     = (const float*)d_in[23];
    const float* ffn_b2     = (const float*)d_in[24];

    char* w = (char*)d_ws;
    float4* rowred = (float4*)(w + 0);                         // 128 KB
    float*  xsq    = (float*)(w + 131072);                     // 32 KB
    float*  topo_add = (float*)(w + 163840);                   // 48 KB
    size_t off = 212992;
    short* wT_ip = (short*)(w + off); off += (size_t)3 * Dz * Dz * 2;
    short* wT_op = (short*)(w + off); off += (size_t)Dz * Dz * 2;
    short* wT_f1 = (short*)(w + off); off += (size_t)2 * Dz * Dz * 2;
    short* wT_f2 = (short*)(w + off); off += (size_t)2 * Dz * Dz * 2;
    short* scb   = (short*)(w + off); off += (size_t)Bz * NSz * Dz * 2;        // gathered samples bf16
    float* Dd    = (float*)(w + off); off += (size_t)Bz * Sz * NSz * 4;        // distances fp32
    char*  qkv0  = w + off;           off += (size_t)3 * Bz * Sz * Dz * 2;     // q,k,vT then x1b,hb
    short* qbuf  = (short*)qkv0;
    short* kbuf  = (short*)(qkv0 + (size_t)Bz * Sz * Dz * 2);
    short* vTbuf = (short*)(qkv0 + (size_t)2 * Bz * Sz * Dz * 2);
    short* x1b   = (short*)qkv0;                                               // reuse (after attn)
    short* hb    = (short*)(qkv0 + (size_t)Bz * Sz * Dz * 2);                  // [8192][1536]
    short* xb    = (short*)(w + off); off += (size_t)Bz * Sz * Dz * 2;         // bf16 x; reused as ob
    short* ob    = xb;
    short* apb   = (short*)(w + off); off += (size_t)Bz * Sz * Dz * 2;         // out_proj bf16
    short* f2b   = (short*)(w + off); off += (size_t)Bz * Sz * Dz * 2;         // ffn2 bf16

    const int M = Bz * Sz;   // 8192

    xrn_k<<<M / 4, 256, 0, stream>>>(x, xb, xsq);
    prep_k<<<1280, 256, 0, stream>>>(in_proj_w, out_proj_w, ffn_w1, ffn_w2,
                                     wT_ip, wT_op, wT_f1, wT_f2, x, sidx, scb);
    // LSH distances via bf16 MFMA (batched BT = scb per batch)
    mgemm_k<4><<<M / 256, 512, 0, stream>>>(xb, scb, nullptr, Dd, nullptr,
                                            NSz, Dz, 1, nullptr, nullptr, nullptr, sidx, xsq);
    knnstat_k<<<M, 128, 0, stream>>>(Dd, rowred);
    land_topo_k<<<Bz, 256, 0, stream>>>(rowred, w1, b1, w2, b2,
                                        wd0, bd0, topo_w, topo_b, gate, topo_add);
    // qkv projection (scatter to q,k row-major + v transposed, bf16)
    mgemm_k<2><<<(3 * Dz / 128) * (M / 256), 512, 0, stream>>>(xb, wT_ip, in_proj_b,
                                                               nullptr, nullptr, 3 * Dz, Dz, 3 * Dz / 128,
                                                               qbuf, kbuf, vTbuf, nullptr, nullptr);
    attn4_k<<<Bz * Hz * 8, 256, 0, stream>>>(qbuf, kbuf, vTbuf, ob);
    // out proj -> bf16
    mgemm_k<3><<<(Dz / 128) * (M / 256), 512, 0, stream>>>(ob, wT_op, out_proj_b,
                                                           nullptr, apb, Dz, Dz, Dz / 128,
                                                           nullptr, nullptr, nullptr, nullptr, nullptr);
    ln1_k<<<M / 4, 256, 0, stream>>>(x, apb, topo_add, ln1_g, ln1_b, x1b);
    // ffn1 -> gelu -> bf16
    mgemm_k<1><<<(2 * Dz / 128) * (M / 256), 512, 0, stream>>>(x1b, wT_f1, ffn_b1,
                                                               nullptr, hb, 2 * Dz, Dz, 2 * Dz / 128,
                                                               nullptr, nullptr, nullptr, nullptr, nullptr);
    // ffn2 -> bf16
    mgemm_k<3><<<(Dz / 128) * (M / 256), 512, 0, stream>>>(hb, wT_f2, ffn_b2,
                                                           nullptr, f2b, Dz, 2 * Dz, Dz / 128,
                                                           nullptr, nullptr, nullptr, nullptr, nullptr);
    ln2_k<<<M / 4, 256, 0, stream>>>(x1b, f2b, ln2_g, ln2_b, (float*)d_out);
}

// Round 11
// 386.694 us; speedup vs baseline: 1.0356x; 1.0356x over previous
//
#include <hip/hip_runtime.h>
#include <math.h>

#define Bz 16
#define Sz 512
#define Dz 768
#define Hz 12
#define HDz 64
#define Kz 16
#define NSz 128
#define Rz 32

typedef __attribute__((ext_vector_type(4))) float f32x4;
typedef __attribute__((ext_vector_type(8))) short bf16x8;

__device__ __forceinline__ unsigned short f2bf(float f) {
    unsigned u = __float_as_uint(f);
    return (unsigned short)((u + 0x7fffu + ((u >> 16) & 1u)) >> 16);
}
__device__ __forceinline__ float bf2f(unsigned short s) {
    return __uint_as_float(((unsigned)s) << 16);
}
__device__ __forceinline__ unsigned pk2(float a, float b) {
    return (unsigned)f2bf(a) | ((unsigned)f2bf(b) << 16);
}
__device__ __forceinline__ void gload_lds16(const void* g, void* l) {
    __builtin_amdgcn_global_load_lds(
        (const __attribute__((address_space(1))) unsigned int*)g,
        (__attribute__((address_space(3))) unsigned int*)l, 16, 0, 0);
}

// ---------------- fused x->bf16 + row squared norms (one wave per row) ----------------
__global__ __launch_bounds__(256) void xrn_k(const float* __restrict__ x, short* __restrict__ xb,
                                             float* __restrict__ xsq) {
    int wv = threadIdx.x >> 6, lane = threadIdx.x & 63;
    int row = blockIdx.x * 4 + wv;
    const float* r = x + (size_t)row * Dz;
    unsigned long long* dst = (unsigned long long*)(xb + (size_t)row * Dz);
    float s = 0.f;
#pragma unroll
    for (int j = 0; j < 3; j++) {
        float4 v = ((const float4*)r)[lane + j * 64];
        s += v.x * v.x + v.y * v.y + v.z * v.z + v.w * v.w;
        dst[lane + j * 64] = (unsigned long long)pk2(v.x, v.y) | ((unsigned long long)pk2(v.z, v.w) << 32);
    }
#pragma unroll
    for (int off = 32; off > 0; off >>= 1) s += __shfl_xor(s, off, 64);
    if (lane == 0) xsq[row] = s;
}

// ---------------- prep: 4 weight transposes (fp32->bf16, [n][k]) + sample gather ----------------
__device__ __forceinline__ void wtrans_body(const float* __restrict__ src, short* __restrict__ dst,
                                            int K, int N, int k0, int n0, int tid,
                                            float (*t)[65]) {
#pragma unroll
    for (int i = 0; i < 16; i++) {
        int e = tid + 256 * i;
        int kk = e >> 6, nn = e & 63;
        t[kk][nn] = src[(size_t)(k0 + kk) * N + n0 + nn];
    }
    __syncthreads();
#pragma unroll
    for (int i = 0; i < 16; i++) {
        int e = tid + 256 * i;
        int nn = e >> 6, kk = e & 63;
        dst[(size_t)(n0 + nn) * K + k0 + kk] = (short)f2bf(t[kk][nn]);
    }
}

__global__ __launch_bounds__(256) void prep_k(const float* __restrict__ ipw, const float* __restrict__ opw,
                                              const float* __restrict__ f1w, const float* __restrict__ f2w,
                                              short* __restrict__ wT_ip, short* __restrict__ wT_op,
                                              short* __restrict__ wT_f1, short* __restrict__ wT_f2,
                                              const float* __restrict__ x, const int* __restrict__ sidx,
                                              short* __restrict__ scb) {
    __shared__ float t[64][65];
    int bid = blockIdx.x, tid = threadIdx.x;
    if (bid < 432) {
        int lo = bid, tx = lo % 36, ty = lo / 36;
        wtrans_body(ipw, wT_ip, Dz, 3 * Dz, ty * 64, tx * 64, tid, t);
    } else if (bid < 576) {
        int lo = bid - 432, tx = lo % 12, ty = lo / 12;
        wtrans_body(opw, wT_op, Dz, Dz, ty * 64, tx * 64, tid, t);
    } else if (bid < 864) {
        int lo = bid - 576, tx = lo % 24, ty = lo / 24;
        wtrans_body(f1w, wT_f1, Dz, 2 * Dz, ty * 64, tx * 64, tid, t);
    } else if (bid < 1152) {
        int lo = bid - 864, tx = lo % 12, ty = lo / 12;
        wtrans_body(f2w, wT_f2, 2 * Dz, Dz, ty * 64, tx * 64, tid, t);
    } else {
        int gb = bid - 1152;
        int row = gb * 16 + (tid >> 4);
        int b = row >> 7, jj = row & 127;
        const float* src = x + ((size_t)(b * Sz) + sidx[jj]) * Dz;
        unsigned long long* dr = (unsigned long long*)(scb + (size_t)row * Dz);
        int l16 = tid & 15;
#pragma unroll
        for (int j = 0; j < 12; j++) {
            int idx = j * 16 + l16;
            float4 v = ((const float4*)src)[idx];
            dr[idx] = (unsigned long long)pk2(v.x, v.y) | ((unsigned long long)pk2(v.z, v.w) << 32);
        }
    }
}

// ---------------- rank-select K smallest -> per-row {sum, sumsq, min, max16} ----------------
__global__ __launch_bounds__(128) void knnstat_k(const float* __restrict__ D, float4* __restrict__ rowred) {
    __shared__ float dv[NSz];
    __shared__ float red[NSz], red2[NSz];
    __shared__ float rmin, rmax;
    int tid = threadIdx.x, row = blockIdx.x;
    float dist = D[(size_t)row * NSz + tid];
    dv[tid] = dist;
    __syncthreads();
    int rank = 0;
#pragma unroll 8
    for (int j = 0; j < NSz; j++) {
        float o = dv[j];
        rank += (o < dist) || (o == dist && j < tid);
    }
    if (rank == 0) rmin = dist;
    if (rank == Kz - 1) rmax = dist;
    red[tid] = (rank < Kz) ? dist : 0.f;
    red2[tid] = (rank < Kz) ? dist * dist : 0.f;
    __syncthreads();
    for (int st = 64; st > 0; st >>= 1) {
        if (tid < st) { red[tid] += red[tid + st]; red2[tid] += red2[tid + st]; }
        __syncthreads();
    }
    if (tid == 0) rowred[row] = make_float4(red[0], red2[0], rmin, rmax);
}

// ---------------- per-batch reduce + stats -> landscape MLP -> topo vector ----------------
__global__ __launch_bounds__(256) void land_topo_k(const float4* __restrict__ rowred,
                                                   const float* __restrict__ w1, const float* __restrict__ b1,
                                                   const float* __restrict__ w2, const float* __restrict__ b2,
                                                   const float* __restrict__ wd0, const float* __restrict__ bd0,
                                                   const float* __restrict__ topo_w, const float* __restrict__ topo_b,
                                                   const float* gate, float* __restrict__ topo_add) {
    __shared__ float4 red4[256];
    __shared__ float st[6];
    __shared__ float h[Dz / 4];
    __shared__ float l2[Rz];
    __shared__ float land[Rz];
    int b = blockIdx.x, tid = threadIdx.x;
    float4 a = rowred[b * Sz + tid];
    float4 c = rowred[b * Sz + 256 + tid];
    float4 r;
    r.x = a.x + c.x; r.y = a.y + c.y;
    r.z = fminf(a.z, c.z); r.w = fmaxf(a.w, c.w);
    red4[tid] = r;
    __syncthreads();
    for (int stp = 128; stp > 0; stp >>= 1) {
        if (tid < stp) {
            float4 p = red4[tid], q = red4[tid + stp];
            p.x += q.x; p.y += q.y; p.z = fminf(p.z, q.z); p.w = fmaxf(p.w, q.w);
            red4[tid] = p;
        }
        __syncthreads();
    }
    if (tid == 0) {
        const double N = (double)(Sz * Kz);
        double sum = (double)red4[0].x, sumsq = (double)red4[0].y;
        double mean = sum / N;
        double var = (sumsq - N * mean * mean) / (N - 1.0);
        float sd = (float)sqrt(fmax(var, 0.0));
        float m = (float)mean;
        st[0] = m; st[1] = sd;
        st[2] = red4[0].z; st[3] = red4[0].w;
        st[4] = m * 0.5f; st[5] = sd * 0.5f;
    }
    __syncthreads();
    if (tid < Dz / 4) {
        float a1 = b1[tid];
#pragma unroll
        for (int i = 0; i < 6; i++) a1 += st[i] * w1[i * (Dz / 4) + tid];
        h[tid] = fmaxf(a1, 0.f);
    }
    __syncthreads();
    if (tid < Rz) {
        float a1 = b2[tid];
        for (int i = 0; i < Dz / 4; i++) a1 += h[i] * w2[i * Rz + tid];
        l2[tid] = a1;
    }
    __syncthreads();
    if (tid < Rz) {
        float a1 = bd0[tid];
#pragma unroll
        for (int i = 0; i < Rz; i++) a1 += l2[i] * wd0[i * Rz + tid];
        land[tid] = a1;
    }
    __syncthreads();
    float g = gate[0];
    for (int d = tid; d < Dz; d += 256) {
        float a1 = topo_b[d];
#pragma unroll
        for (int i = 0; i < Rz; i++) a1 += land[i] * topo_w[i * Dz + d];
        topo_add[b * Dz + d] = g * a1;
    }
}

// ---------------- MFMA GEMM 256x128 tile, 8 waves, 3-buffer counted-vmcnt pipeline ----------------
// EPI: 1 = GELU->bf16 (restaged), 2 = qkv scatter (restaged), 3 = bf16 store (restaged),
//      4 = LSH distance epilogue (fp32 sqrt, batched BT)
// Each stage() issues exactly 3 global_load_lds per thread. Buffer rotation (t+2)%3 with
// s_waitcnt vmcnt(3) before raw s_barrier keeps the next stage's loads in flight across
// the barrier (T4; avoids the compiler's vmcnt(0) drain). sched_barrier(0) pins per rule #18.
__device__ __forceinline__ void stage_tile256(const short* __restrict__ A, const short* __restrict__ B,
                                              int ldk, int m0, int n0, int k0,
                                              short* lbase, int w, int l) {
#pragma unroll
    for (int si = 0; si < 3; si++) {
        int s = si * 8 + w;
        if (s < 16) {
            int r = s * 16 + (l >> 2);
            int qg = (l & 3) ^ ((r >> 1) & 3);
            gload_lds16(A + (size_t)(m0 + r) * ldk + k0 + qg * 8, lbase + s * 512);
        } else {
            int r = (s - 16) * 16 + (l >> 2);
            int qg = (l & 3) ^ ((r >> 1) & 3);
            gload_lds16(B + (size_t)(n0 + r) * ldk + k0 + qg * 8, lbase + 8192 + (s - 16) * 512);
        }
    }
}

template <int EPI>
__global__ __launch_bounds__(512) void mgemm_k(const short* __restrict__ A, const short* __restrict__ BT,
                                               const float* __restrict__ bias,
                                               float* __restrict__ C, short* __restrict__ Cb,
                                               int N, int Kd, int gx,
                                               short* __restrict__ qo, short* __restrict__ ko,
                                               short* __restrict__ vT,
                                               const int* __restrict__ sidx, const float* __restrict__ xsq) {
    __shared__ short lds[3][12288];
    int tid = threadIdx.x, w = tid >> 6, l = tid & 63;
    int nwg = gridDim.x, q = nwg >> 3;
    int orig = (blockIdx.x & 7) * q + (blockIdx.x >> 3);
    int m0 = (orig / gx) * 256, n0 = (orig % gx) * 128;
    const short* BTb = BT;
    if (EPI == 4) BTb += (size_t)(m0 >> 9) * NSz * Kd;
    int wr = w >> 1, wc = w & 1, g = l >> 4, ql = l & 15;
    f32x4 acc[4][4];
#pragma unroll
    for (int i = 0; i < 4; i++)
#pragma unroll
        for (int j = 0; j < 4; j++) acc[i][j] = (f32x4){0.f, 0.f, 0.f, 0.f};
    int nst = Kd / 32;
    // prologue: stage buffers 0 and 1; wait only for buffer 0 (3 of wave's 6 loads)
    stage_tile256(A, BTb, Kd, m0, n0, 0, lds[0], w, l);
    stage_tile256(A, BTb, Kd, m0, n0, 32, lds[1], w, l);
    __builtin_amdgcn_sched_barrier(0);
    asm volatile("s_waitcnt vmcnt(3)" ::: "memory");
    __builtin_amdgcn_sched_barrier(0);
    __builtin_amdgcn_s_barrier();
    __builtin_amdgcn_sched_barrier(0);
    int buf = 0;
    for (int t = 0; t < nst; t++) {
        if (t + 2 < nst) {
            int nb = buf + 2; if (nb >= 3) nb -= 3;
            stage_tile256(A, BTb, Kd, m0, n0, (t + 2) * 32, lds[nb], w, l);
        }
        bf16x8 af[4], bfr[4];
#pragma unroll
        for (int i = 0; i < 4; i++) {
            int r = wr * 64 + i * 16 + ql;
            af[i] = *(const bf16x8*)((const char*)lds[buf] + r * 64 + ((g ^ ((r >> 1) & 3)) << 4));
        }
#pragma unroll
        for (int j = 0; j < 4; j++) {
            int r = wc * 64 + j * 16 + ql;
            bfr[j] = *(const bf16x8*)((const char*)lds[buf] + 16384 + r * 64 + ((g ^ ((r >> 1) & 3)) << 4));
        }
#pragma unroll
        for (int i = 0; i < 4; i++)
#pragma unroll
            for (int j = 0; j < 4; j++)
                acc[i][j] = __builtin_amdgcn_mfma_f32_16x16x32_bf16(af[i], bfr[j], acc[i][j], 0, 0, 0);
        __builtin_amdgcn_sched_barrier(0);
        if (t + 2 < nst) {
            asm volatile("s_waitcnt vmcnt(3)" ::: "memory");   // older stage (t+1) landed; t+2 in flight
        } else {
            asm volatile("s_waitcnt vmcnt(0)" ::: "memory");   // tail: drain
        }
        __builtin_amdgcn_sched_barrier(0);
        __builtin_amdgcn_s_barrier();
        __builtin_amdgcn_sched_barrier(0);
        buf++; if (buf >= 3) buf = 0;
    }

    if (EPI == 4) {
#pragma unroll
        for (int i = 0; i < 4; i++) {
            int rowb = m0 + wr * 64 + i * 16 + g * 4;
            int bb = rowb >> 9;
#pragma unroll
            for (int j = 0; j < 4; j++) {
                int col = wc * 64 + j * 16 + ql;
                float ssq = xsq[(bb << 9) + sidx[col]];
#pragma unroll
                for (int r = 0; r < 4; r++) {
                    int row = rowb + r;
                    float d2 = xsq[row] + ssq - 2.f * acc[i][j][r];
                    C[(size_t)row * NSz + col] = sqrtf(fmaxf(d2, 0.f));
                }
            }
        }
    } else {
        // restage C-tile in two 128-row halves (128x128 bf16 = 32 KB) through staging LDS
        short* cl = lds[0];
        const int part = (EPI == 2) ? (n0 / Dz) : 0;
        const bool cm = (EPI == 2) && (part == 2);   // uniform per block
#pragma unroll
        for (int h = 0; h < 2; h++) {
            if ((w >> 2) == h) {
                int wrl = wr & 1;    // 64-row band within this half
                if (!cm) {
#pragma unroll
                    for (int i = 0; i < 4; i++) {
#pragma unroll
                        for (int j = 0; j < 4; j++) {
                            int colL = wc * 64 + j * 16 + ql;
                            float bsv = bias[n0 + colL];
#pragma unroll
                            for (int r = 0; r < 4; r++) {
                                int rowL = wrl * 64 + i * 16 + g * 4 + r;
                                float val = acc[i][j][r] + bsv;
                                if (EPI == 1) val = 0.5f * val * (1.f + erff(val * 0.70710678118654752f));
                                cl[rowL * 128 + (((colL >> 3) ^ (rowL & 15)) << 3) + (colL & 7)] = (short)f2bf(val);
                            }
                        }
                    }
                } else {
#pragma unroll
                    for (int i = 0; i < 4; i++) {
#pragma unroll
                        for (int j = 0; j < 4; j++) {
                            int colL = wc * 64 + j * 16 + ql;
                            float bsv = bias[n0 + colL];
                            int row4 = wrl * 64 + i * 16 + g * 4;
                            unsigned long long u =
                                (unsigned long long)pk2(acc[i][j][0] + bsv, acc[i][j][1] + bsv)
                              | ((unsigned long long)pk2(acc[i][j][2] + bsv, acc[i][j][3] + bsv) << 32);
                            *(unsigned long long*)((char*)cl +
                                colL * 256 + (((row4 >> 3) ^ (colL & 15)) << 4) + (row4 & 7) * 2) = u;
                        }
                    }
                }
            }
            __syncthreads();
            int rbase = m0 + h * 128;
#pragma unroll
            for (int it = 0; it < 4; it++) {
                int c = tid + 512 * it;
                int a = c >> 4, sl = c & 15;
                bf16x8 vv = *(const bf16x8*)(cl + a * 128 + ((sl ^ (a & 15)) << 3));
                if (EPI == 1 || EPI == 3) {
                    *(bf16x8*)(Cb + (size_t)(rbase + a) * N + n0 + sl * 8) = vv;
                } else if (!cm) {
                    int rr = rbase + a;
                    int b = rr >> 9, s = rr & 511;
                    int hh = ((n0 % Dz) >> 6) + (sl >> 3);
                    short* dst = part ? ko : qo;
                    *(bf16x8*)(dst + (((size_t)(b * Hz + hh)) * Sz + s) * HDz + (sl & 7) * 8) = vv;
                } else {
                    int wi = (n0 - 2 * Dz) + a;
                    int hh = wi >> 6, hd = wi & 63;
                    int b = rbase >> 9, s0 = (rbase & 511) + sl * 8;
                    *(bf16x8*)(vT + ((size_t)(b * Hz + hh) * HDz + hd) * Sz + s0) = vv;
                }
            }
            if (h == 0) __syncthreads();
        }
    }
}

// ---------------- MFMA attention v4: LDS-staged K/V chunks, XCD-local heads ----------------
__global__ __launch_bounds__(256, 4) void attn4_k(const short* __restrict__ Q, const short* __restrict__ Kt,
                                                  const short* __restrict__ Vt, short* __restrict__ O) {
    __shared__ short kl[2][4096];
    __shared__ short vl[2][4096];
    __shared__ char plds[4][2048];
    int tid = threadIdx.x, w = tid >> 6, l = tid & 63;
    int bh = blockIdx.x % (Bz * Hz), qt = blockIdx.x / (Bz * Hz);
    int g = l >> 4, ql = l & 15;
    const short* qb = Q + (size_t)bh * (Sz * HDz) + (size_t)(qt * 64 + w * 16) * HDz;
    const short* kb = Kt + (size_t)bh * (Sz * HDz);
    const short* vb = Vt + (size_t)bh * (HDz * Sz);
    bf16x8 qf0 = *(const bf16x8*)(qb + (size_t)ql * HDz + g * 8);
    bf16x8 qf1 = *(const bf16x8*)(qb + (size_t)ql * HDz + 32 + g * 8);
    f32x4 oa[4];
#pragma unroll
    for (int m = 0; m < 4; m++) oa[m] = (f32x4){0.f, 0.f, 0.f, 0.f};
    float psum = 0.f;

    auto stage = [&](int c, int bb) {
#pragma unroll
        for (int it = 0; it < 2; it++) {
            int i = (it * 4 + w) * 64 + l;
            int row = i >> 3;
            int ss = (i & 7) ^ (row & 7);
            gload_lds16(kb + (size_t)(c * 64 + row) * HDz + ss * 8,
                        (char*)kl[bb] + (it * 4 + w) * 1024);
            gload_lds16(vb + (size_t)row * Sz + c * 64 + ss * 8,
                        (char*)vl[bb] + (it * 4 + w) * 1024);
        }
    };

    stage(0, 0);
    __syncthreads();
    char* pw = plds[w];
#pragma unroll
    for (int c = 0; c < 8; c++) {
        int cur = c & 1;
        if (c < 7) stage(c + 1, cur ^ 1);
        const char* kc = (const char*)kl[cur];
        const char* vc = (const char*)vl[cur];
#pragma unroll
        for (int tl = 0; tl < 4; tl++) {
            int row = tl * 16 + ql;
            bf16x8 a0 = *(const bf16x8*)(kc + row * 128 + ((g ^ (ql & 7)) << 4));
            bf16x8 a1 = *(const bf16x8*)(kc + row * 128 + (((4 + g) ^ (ql & 7)) << 4));
            f32x4 s4 = (f32x4){0.f, 0.f, 0.f, 0.f};
            s4 = __builtin_amdgcn_mfma_f32_16x16x32_bf16(a0, qf0, s4, 0, 0, 0);
            s4 = __builtin_amdgcn_mfma_f32_16x16x32_bf16(a1, qf1, s4, 0, 0, 0);
            float e0 = __expf(s4[0] * 0.125f);
            float e1 = __expf(s4[1] * 0.125f);
            float e2 = __expf(s4[2] * 0.125f);
            float e3 = __expf(s4[3] * 0.125f);
            psum += (e0 + e1) + (e2 + e3);
            int slot = (tl * 2 + (g >> 1)) ^ (ql & 7);
            *(unsigned long long*)(pw + ql * 128 + slot * 16 + (g & 1) * 8)
                = (unsigned long long)pk2(e0, e1) | ((unsigned long long)pk2(e2, e3) << 32);
        }
#pragma unroll
        for (int s = 0; s < 2; s++) {
            int slot = (s * 4 + g) ^ (ql & 7);
            bf16x8 pb = *(const bf16x8*)(pw + ql * 128 + slot * 16);
#pragma unroll
            for (int m = 0; m < 4; m++) {
                int row = m * 16 + ql;
                bf16x8 va = *(const bf16x8*)(vc + row * 128 + (((s * 4 + g) ^ (ql & 7)) << 4));
                oa[m] = __builtin_amdgcn_mfma_f32_16x16x32_bf16(va, pb, oa[m], 0, 0, 0);
            }
        }
        __syncthreads();
    }
    psum += __shfl_xor(psum, 16, 64);
    psum += __shfl_xor(psum, 32, 64);
    float inv = 1.f / psum;
    int b = bh / Hz, h = bh % Hz;
    int s = qt * 64 + w * 16 + ql;
#pragma unroll
    for (int m = 0; m < 4; m++)
#pragma unroll
        for (int j = 0; j < 2; j++) {
            float v0 = oa[m][j * 2] * inv, v1 = oa[m][j * 2 + 1] * inv;
            unsigned u = pk2(v0, v1);
            int d = h * 64 + m * 16 + g * 4 + j * 2;
            *(unsigned*)((char*)O + 2 * ((size_t)(b * Sz + s) * Dz + d)) = u;
        }
}

// ---------------- LN1 (wave/row, vectorized, one-pass): x1b = bf16(LN(x + bf2f(ap) + topo)) ----------------
__global__ __launch_bounds__(256) void ln1_k(const float* __restrict__ x, const short* __restrict__ ap,
                                             const float* __restrict__ topo,
                                             const float* __restrict__ gam, const float* __restrict__ bet,
                                             short* __restrict__ x1b) {
    int wv = threadIdx.x >> 6, lane = threadIdx.x & 63;
    int row = blockIdx.x * 4 + wv, b = row >> 9;
    const float4* xr = (const float4*)(x + (size_t)row * Dz);
    const float4* tr = (const float4*)(topo + (size_t)b * Dz);
    const unsigned long long* ar = (const unsigned long long*)(ap + (size_t)row * Dz);
    float v[12];
    float sum = 0.f, ssq = 0.f;
#pragma unroll
    for (int j = 0; j < 3; j++) {
        int idx = lane + j * 64;
        float4 xv = xr[idx];
        float4 tv = tr[idx];
        unsigned long long av = ar[idx];
        float v0 = xv.x + bf2f((unsigned short)av) + tv.x;
        float v1 = xv.y + bf2f((unsigned short)(av >> 16)) + tv.y;
        float v2 = xv.z + bf2f((unsigned short)(av >> 32)) + tv.z;
        float v3 = xv.w + bf2f((unsigned short)(av >> 48)) + tv.w;
        v[j * 4 + 0] = v0; v[j * 4 + 1] = v1; v[j * 4 + 2] = v2; v[j * 4 + 3] = v3;
        sum += (v0 + v1) + (v2 + v3);
        ssq += (v0 * v0 + v1 * v1) + (v2 * v2 + v3 * v3);
    }
#pragma unroll
    for (int off = 32; off > 0; off >>= 1) {
        sum += __shfl_xor(sum, off, 64);
        ssq += __shfl_xor(ssq, off, 64);
    }
    float mean = sum * (1.f / (float)Dz);
    float var = ssq * (1.f / (float)Dz) - mean * mean;
    float inv = 1.f / sqrtf(var + 1e-5f);
    unsigned long long* dst = (unsigned long long*)(x1b + (size_t)row * Dz);
#pragma unroll
    for (int j = 0; j < 3; j++) {
        int idx = lane + j * 64;
        float4 gv = ((const float4*)gam)[idx];
        float4 bv = ((const float4*)bet)[idx];
        float o0 = (v[j * 4 + 0] - mean) * inv * gv.x + bv.x;
        float o1 = (v[j * 4 + 1] - mean) * inv * gv.y + bv.y;
        float o2 = (v[j * 4 + 2] - mean) * inv * gv.z + bv.z;
        float o3 = (v[j * 4 + 3] - mean) * inv * gv.w + bv.w;
        dst[idx] = (unsigned long long)pk2(o0, o1) | ((unsigned long long)pk2(o2, o3) << 32);
    }
}

// ---------------- LN2 (wave/row, vectorized, one-pass): out = LN(bf2f(x1b) + bf2f(f2)) ----------------
__global__ __launch_bounds__(256) void ln2_k(const short* __restrict__ x1b, const short* __restrict__ f2,
                                             const float* __restrict__ gam, const float* __restrict__ bet,
                                             float* __restrict__ out) {
    int wv = threadIdx.x >> 6, lane = threadIdx.x & 63;
    int row = blockIdx.x * 4 + wv;
    const unsigned long long* xr = (const unsigned long long*)(x1b + (size_t)row * Dz);
    const unsigned long long* fr = (const unsigned long long*)(f2 + (size_t)row * Dz);
    float v[12];
    float sum = 0.f, ssq = 0.f;
#pragma unroll
    for (int j = 0; j < 3; j++) {
        int idx = lane + j * 64;
        unsigned long long xv = xr[idx];
        unsigned long long fv = fr[idx];
        float v0 = bf2f((unsigned short)xv) + bf2f((unsigned short)fv);
        float v1 = bf2f((unsigned short)(xv >> 16)) + bf2f((unsigned short)(fv >> 16));
        float v2 = bf2f((unsigned short)(xv >> 32)) + bf2f((unsigned short)(fv >> 32));
        float v3 = bf2f((unsigned short)(xv >> 48)) + bf2f((unsigned short)(fv >> 48));
        v[j * 4 + 0] = v0; v[j * 4 + 1] = v1; v[j * 4 + 2] = v2; v[j * 4 + 3] = v3;
        sum += (v0 + v1) + (v2 + v3);
        ssq += (v0 * v0 + v1 * v1) + (v2 * v2 + v3 * v3);
    }
#pragma unroll
    for (int off = 32; off > 0; off >>= 1) {
        sum += __shfl_xor(sum, off, 64);
        ssq += __shfl_xor(ssq, off, 64);
    }
    float mean = sum * (1.f / (float)Dz);
    float var = ssq * (1.f / (float)Dz) - mean * mean;
    float inv = 1.f / sqrtf(var + 1e-5f);
    float4* dst = (float4*)(out + (size_t)row * Dz);
#pragma unroll
    for (int j = 0; j < 3; j++) {
        int idx = lane + j * 64;
        float4 gv = ((const float4*)gam)[idx];
        float4 bv = ((const float4*)bet)[idx];
        float4 o;
        o.x = (v[j * 4 + 0] - mean) * inv * gv.x + bv.x;
        o.y = (v[j * 4 + 1] - mean) * inv * gv.y + bv.y;
        o.z = (v[j * 4 + 2] - mean) * inv * gv.z + bv.z;
        o.w = (v[j * 4 + 3] - mean) * inv * gv.w + bv.w;
        dst[idx] = o;
    }
}

extern "C" void kernel_launch(void* const* d_in, const int* in_sizes, int n_in,
                              void* d_out, int out_size, void* d_ws, size_t ws_size,
                              hipStream_t stream) {
    const float* x          = (const float*)d_in[0];
    const int*   sidx       = (const int*)d_in[1];
    const float* w1         = (const float*)d_in[2];
    const float* b1         = (const float*)d_in[3];
    const float* w2         = (const float*)d_in[4];
    const float* b2         = (const float*)d_in[5];
    const float* wd0        = (const float*)d_in[6];
    const float* bd0        = (const float*)d_in[7];
    const float* in_proj_w  = (const float*)d_in[10];
    const float* in_proj_b  = (const float*)d_in[11];
    const float* out_proj_w = (const float*)d_in[12];
    const float* out_proj_b = (const float*)d_in[13];
    const float* topo_w     = (const float*)d_in[14];
    const float* topo_b     = (const float*)d_in[15];
    const float* gate       = (const float*)d_in[16];
    const float* ln1_g      = (const float*)d_in[17];
    const float* ln1_b      = (const float*)d_in[18];
    const float* ln2_g      = (const float*)d_in[19];
    const float* ln2_b      = (const float*)d_in[20];
    const float* ffn_w1     = (const float*)d_in[21];
    const float* ffn_b1     = (const float*)d_in[22];
    const float* ffn_w2     = (const float*)d_in[23];
    const float* ffn_b2     = (const float*)d_in[24];

    char* w = (char*)d_ws;
    float4* rowred = (float4*)(w + 0);                         // 128 KB
    float*  xsq    = (float*)(w + 131072);                     // 32 KB
    float*  topo_add = (float*)(w + 163840);                   // 48 KB
    size_t off = 212992;
    short* wT_ip = (short*)(w + off); off += (size_t)3 * Dz * Dz * 2;
    short* wT_op = (short*)(w + off); off += (size_t)Dz * Dz * 2;
    short* wT_f1 = (short*)(w + off); off += (size_t)2 * Dz * Dz * 2;
    short* wT_f2 = (short*)(w + off); off += (size_t)2 * Dz * Dz * 2;
    short* scb   = (short*)(w + off); off += (size_t)Bz * NSz * Dz * 2;        // gathered samples bf16
    float* Dd    = (float*)(w + off); off += (size_t)Bz * Sz * NSz * 4;        // distances fp32
    char*  qkv0  = w + off;           off += (size_t)3 * Bz * Sz * Dz * 2;     // q,k,vT then x1b,hb
    short* qbuf  = (short*)qkv0;
    short* kbuf  = (short*)(qkv0 + (size_t)Bz * Sz * Dz * 2);
    short* vTbuf = (short*)(qkv0 + (size_t)2 * Bz * Sz * Dz * 2);
    short* x1b   = (short*)qkv0;                                               // reuse (after attn)
    short* hb    = (short*)(qkv0 + (size_t)Bz * Sz * Dz * 2);                  // [8192][1536]
    short* xb    = (short*)(w + off); off += (size_t)Bz * Sz * Dz * 2;         // bf16 x; reused as ob
    short* ob    = xb;
    short* apb   = (short*)(w + off); off += (size_t)Bz * Sz * Dz * 2;         // out_proj bf16
    short* f2b   = (short*)(w + off); off += (size_t)Bz * Sz * Dz * 2;         // ffn2 bf16

    const int M = Bz * Sz;   // 8192

    xrn_k<<<M / 4, 256, 0, stream>>>(x, xb, xsq);
    prep_k<<<1280, 256, 0, stream>>>(in_proj_w, out_proj_w, ffn_w1, ffn_w2,
                                     wT_ip, wT_op, wT_f1, wT_f2, x, sidx, scb);
    // LSH distances via bf16 MFMA (batched BT = scb per batch)
    mgemm_k<4><<<M / 256, 512, 0, stream>>>(xb, scb, nullptr, Dd, nullptr,
                                            NSz, Dz, 1, nullptr, nullptr, nullptr, sidx, xsq);
    knnstat_k<<<M, 128, 0, stream>>>(Dd, rowred);
    land_topo_k<<<Bz, 256, 0, stream>>>(rowred, w1, b1, w2, b2,
                                        wd0, bd0, topo_w, topo_b, gate, topo_add);
    // qkv projection (scatter to q,k row-major + v transposed, bf16)
    mgemm_k<2><<<(3 * Dz / 128) * (M / 256), 512, 0, stream>>>(xb, wT_ip, in_proj_b,
                                                               nullptr, nullptr, 3 * Dz, Dz, 3 * Dz / 128,
                                                               qbuf, kbuf, vTbuf, nullptr, nullptr);
    attn4_k<<<Bz * Hz * 8, 256, 0, stream>>>(qbuf, kbuf, vTbuf, ob);
    // out proj -> bf16
    mgemm_k<3><<<(Dz / 128) * (M / 256), 512, 0, stream>>>(ob, wT_op, out_proj_b,
                                                           nullptr, apb, Dz, Dz, Dz / 128,
                                                           nullptr, nullptr, nullptr, nullptr, nullptr);
    ln1_k<<<M / 4, 256, 0, stream>>>(x, apb, topo_add, ln1_g, ln1_b, x1b);
    // ffn1 -> gelu -> bf16
    mgemm_k<1><<<(2 * Dz / 128) * (M / 256), 512, 0, stream>>>(x1b, wT_f1, ffn_b1,
                                                               nullptr, hb, 2 * Dz, Dz, 2 * Dz / 128,
                                                               nullptr, nullptr, nullptr, nullptr, nullptr);
    // ffn2 -> bf16
    mgemm_k<3><<<(Dz / 128) * (M / 256), 512, 0, stream>>>(hb, wT_f2, ffn_b2,
                                                           nullptr, f2b, Dz, 2 * Dz, Dz / 128,
                                                           nullptr, nullptr, nullptr, nullptr, nullptr);
    ln2_k<<<M / 4, 256, 0, stream>>>(x1b, f2b, ln2_g, ln2_b, (float*)d_out);
}